// Round 3
// baseline (623.008 us; speedup 1.0000x reference)
//
#include <hip/hip_runtime.h>
#include <stdint.h>

// ---------------------------------------------------------------------------
// GPT-2 block, runtime dtype-adaptive (fp32 or bf16 external storage),
// bf16 internal, fp32 accumulate. MI355X / gfx950.
// ---------------------------------------------------------------------------

typedef __attribute__((ext_vector_type(8))) short bf16x8;   // 8 bf16 (4 VGPRs)
typedef __attribute__((ext_vector_type(8))) unsigned short u16x8;
typedef __attribute__((ext_vector_type(4))) float f32x4;

#define NEG_BIG -30000.0f

__device__ __forceinline__ float b2f(unsigned short u) {
  union { unsigned int i; float f; } c; c.i = ((unsigned int)u) << 16; return c.f;
}
__device__ __forceinline__ unsigned short f2b(float f) {
  union { float f; unsigned int u; } c; c.f = f;
  unsigned int r = c.u + 0x7fffu + ((c.u >> 16) & 1u);   // RNE
  return (unsigned short)(r >> 16);
}
// adaptive external load: f32 flag ? fp32 : bf16
__device__ __forceinline__ float ldx(const void* p, size_t i, int f32) {
  return f32 ? ((const float*)p)[i] : b2f(((const unsigned short*)p)[i]);
}

// ---------------------------------------------------------------------------
// dtype detector: bf16 storage -> nearly all ushorts have exp-field in
// [100,145]; fp32 storage -> only high halves do (~59%). flag=1 means fp32.
// ---------------------------------------------------------------------------
__global__ void detect_k(const unsigned short* __restrict__ x, int* __restrict__ flag) {
  int lane = threadIdx.x;
  int cnt = 0;
#pragma unroll
  for (int j = 0; j < 4; ++j) {
    unsigned e = (x[lane * 4 + j] >> 7) & 0xFF;
    if (e >= 100 && e <= 145) cnt++;
  }
#pragma unroll
  for (int off = 32; off; off >>= 1) cnt += __shfl_down(cnt, off);
  if (lane == 0) *flag = (cnt < 220) ? 1 : 0;
}

// ---------------------------------------------------------------------------
// 64x64 tile transpose, adaptive input, bf16 out: out[n*K+k] = in[k*N+n]
// ---------------------------------------------------------------------------
__global__ __launch_bounds__(256) void transpose_k(
    const void* __restrict__ in, unsigned short* __restrict__ out,
    int K, int N, const int* __restrict__ flag) {
  int fm = *flag;
  __shared__ unsigned short tile[64][72];
  int n0 = blockIdx.x * 64, k0 = blockIdx.y * 64;
  int t = threadIdx.x;
  int r = t >> 3, c0 = (t & 7) * 8;
#pragma unroll
  for (int p = 0; p < 2; ++p) {
    int k = r + p * 32;
#pragma unroll
    for (int j = 0; j < 8; ++j)
      tile[k][c0 + j] = f2b(ldx(in, (size_t)(k0 + k) * N + n0 + c0 + j, fm));
  }
  __syncthreads();
#pragma unroll
  for (int p = 0; p < 2; ++p) {
    int n = r + p * 32;
    u16x8 v;
#pragma unroll
    for (int j = 0; j < 8; ++j) v[j] = tile[c0 + j][n];
    *(u16x8*)(out + (size_t)(n0 + n) * K + k0 + c0) = v;
  }
}

// ---------------------------------------------------------------------------
// LayerNorm D=1024; x adaptive iff xAdap, sc/bs always external (adaptive)
// ---------------------------------------------------------------------------
__global__ __launch_bounds__(256) void ln_k(
    const void* __restrict__ x, const void* __restrict__ sc,
    const void* __restrict__ bs, unsigned short* __restrict__ out,
    const int* __restrict__ flag, int xAdap) {
  int fm = *flag;
  int fx = xAdap ? fm : 0;
  int row = blockIdx.x, t = threadIdx.x;
  size_t base = (size_t)row * 1024 + t * 4;
  float f0 = ldx(x, base, fx), f1 = ldx(x, base + 1, fx);
  float f2 = ldx(x, base + 2, fx), f3 = ldx(x, base + 3, fx);
  float s = f0 + f1 + f2 + f3;
  float q = f0 * f0 + f1 * f1 + f2 * f2 + f3 * f3;
#pragma unroll
  for (int off = 32; off; off >>= 1) {
    s += __shfl_down(s, off);
    q += __shfl_down(q, off);
  }
  __shared__ float red[8];
  int w = t >> 6, lane = t & 63;
  if (lane == 0) { red[w] = s; red[w + 4] = q; }
  __syncthreads();
  float S = red[0] + red[1] + red[2] + red[3];
  float Q = red[4] + red[5] + red[6] + red[7];
  float mean = S * (1.f / 1024.f);
  float var = Q * (1.f / 1024.f) - mean * mean;
  float rstd = rsqrtf(var + 1e-5f);
  int c = t * 4;
  ushort4 o;
  o.x = f2b((f0 - mean) * rstd * ldx(sc, c, fm)     + ldx(bs, c, fm));
  o.y = f2b((f1 - mean) * rstd * ldx(sc, c + 1, fm) + ldx(bs, c + 1, fm));
  o.z = f2b((f2 - mean) * rstd * ldx(sc, c + 2, fm) + ldx(bs, c + 2, fm));
  o.w = f2b((f3 - mean) * rstd * ldx(sc, c + 3, fm) + ldx(bs, c + 3, fm));
  ((ushort4*)(out + (size_t)row * 1024))[t] = o;
}

// ---------------------------------------------------------------------------
// GEMM: C[M,N] = A[M,K]*Bt[N,K]^T + bias; EPI: 0=none 1=gelu 2=+res
// A,Bt always bf16 (ws). bias external (adaptive). res adaptive iff resAdap.
// C: fp32 iff (outAdap && fm) else bf16.
// ---------------------------------------------------------------------------
template <int EPI>
__global__ __launch_bounds__(256) void gemm_bt(
    const unsigned short* __restrict__ A, const unsigned short* __restrict__ Bt,
    const void* __restrict__ bias, const void* __restrict__ res,
    void* __restrict__ C, int M, int N, int K,
    const int* __restrict__ flag, int resAdap, int outAdap) {
  int fm = *flag;
  int fr = resAdap ? fm : 0;
  int fo = outAdap ? fm : 0;
  __shared__ unsigned short As[128 * 32];
  __shared__ unsigned short Bs[128 * 32];
  int t = threadIdx.x;
  int bn = blockIdx.x * 128, bm = blockIdx.y * 128;
  int w = t >> 6, lane = t & 63, quad = lane >> 4, l16 = lane & 15;
  int wm = (w >> 1) * 64, wn = (w & 1) * 64;
  f32x4 acc[4][4] = {};

  int c1 = t, c2 = t + 256;
  int r1 = c1 >> 2, e1 = (c1 & 3) * 8;
  int r2 = c2 >> 2, e2 = (c2 & 3) * 8;
  const unsigned short* a1 = A + (size_t)(bm + r1) * K + e1;
  const unsigned short* a2 = A + (size_t)(bm + r2) * K + e2;
  const unsigned short* b1 = Bt + (size_t)(bn + r1) * K + e1;
  const unsigned short* b2 = Bt + (size_t)(bn + r2) * K + e2;

  for (int k0 = 0; k0 < K; k0 += 32) {
    u16x8 va1 = *(const u16x8*)(a1 + k0);
    u16x8 va2 = *(const u16x8*)(a2 + k0);
    u16x8 vb1 = *(const u16x8*)(b1 + k0);
    u16x8 vb2 = *(const u16x8*)(b2 + k0);
    *(u16x8*)(As + c1 * 8) = va1;
    *(u16x8*)(As + c2 * 8) = va2;
    *(u16x8*)(Bs + c1 * 8) = vb1;
    *(u16x8*)(Bs + c2 * 8) = vb2;
    __syncthreads();
    bf16x8 af[4], bfr[4];
#pragma unroll
    for (int i = 0; i < 4; ++i)
      af[i] = *(const bf16x8*)&As[(wm + i * 16 + l16) * 32 + quad * 8];
#pragma unroll
    for (int j = 0; j < 4; ++j)
      bfr[j] = *(const bf16x8*)&Bs[(wn + j * 16 + l16) * 32 + quad * 8];
#pragma unroll
    for (int i = 0; i < 4; ++i)
#pragma unroll
      for (int j = 0; j < 4; ++j)
        acc[i][j] = __builtin_amdgcn_mfma_f32_16x16x32_bf16(af[i], bfr[j], acc[i][j], 0, 0, 0);
    __syncthreads();
  }

  // epilogue: C/D layout col=lane&15, row=quad*4+reg
#pragma unroll
  for (int j = 0; j < 4; ++j) {
    int col = bn + wn + j * 16 + l16;
    float bb = ldx(bias, col, fm);
#pragma unroll
    for (int i = 0; i < 4; ++i) {
      int row0 = bm + wm + i * 16 + quad * 4;
#pragma unroll
      for (int r = 0; r < 4; ++r) {
        float v = acc[i][j][r] + bb;
        if (EPI == 1) {
          float u = 0.7978845608f * (v + 0.044715f * v * v * v);
          float e = __expf(2.f * u);          // tanh(u) = 1 - 2/(e^{2u}+1)
          float th = 1.f - 2.f / (e + 1.f);
          v = 0.5f * v * (1.f + th);
        } else if (EPI == 2) {
          v += ldx(res, (size_t)(row0 + r) * N + col, fr);
        }
        size_t idx = (size_t)(row0 + r) * N + col;
        if (fo) ((float*)C)[idx] = v;
        else    ((unsigned short*)C)[idx] = f2b(v);
      }
    }
  }
}

// ---------------------------------------------------------------------------
// Flash attention, causal. qkv [4096][3072] bf16 (ws). out [4096][1024] bf16.
// ---------------------------------------------------------------------------
__global__ __launch_bounds__(256) void attn_k(
    const unsigned short* __restrict__ qkv, unsigned short* __restrict__ out) {
  constexpr int SD = 72;
  __shared__ unsigned short sm[4608 * 2 + 128 * SD];
  unsigned short* Ks = sm;
  unsigned short* Vs = sm + 4608;
  unsigned short* PQ = sm + 9216;

  int qt = blockIdx.x, bh = blockIdx.y;
  int b = bh >> 4, h = bh & 15;
  const unsigned short* base = qkv + (size_t)b * 2048 * 3072;
  int t = threadIdx.x, w = t >> 6, lane = t & 63, quad = lane >> 4, l16 = lane & 15;
  int wq = w * 32;
  int q0 = qt * 128;

#pragma unroll
  for (int p = 0; p < 4; ++p) {
    int c = p * 256 + t, row = c >> 3, d0 = (c & 7) * 8;
    u16x8 v = *(const u16x8*)(base + (size_t)(q0 + row) * 3072 + h * 64 + d0);
    *(u16x8*)&PQ[row * SD + d0] = v;
  }
  __syncthreads();
  bf16x8 aq[2][2];
#pragma unroll
  for (int i = 0; i < 2; ++i)
#pragma unroll
    for (int kk = 0; kk < 2; ++kk)
      aq[i][kk] = *(const bf16x8*)&PQ[(wq + i * 16 + l16) * SD + kk * 32 + quad * 8];

  float m_i[2][4], l_i[2][4];
  f32x4 Oacc[2][4] = {};
#pragma unroll
  for (int i = 0; i < 2; ++i)
#pragma unroll
    for (int r = 0; r < 4; ++r) { m_i[i][r] = NEG_BIG; l_i[i][r] = 0.f; }

  int ktmax = 2 * (qt + 1);
  for (int kt = 0; kt < ktmax; ++kt) {
#pragma unroll
    for (int p = 0; p < 2; ++p) {
      int c = p * 256 + t, row = c >> 3, d0 = (c & 7) * 8;
      const unsigned short* src = base + (size_t)(kt * 64 + row) * 3072 + h * 64 + d0;
      *(u16x8*)&Ks[row * SD + d0] = *(const u16x8*)(src + 1024);
      *(u16x8*)&Vs[row * SD + d0] = *(const u16x8*)(src + 2048);
    }
    __syncthreads();

    f32x4 S[2][4] = {};
#pragma unroll
    for (int j = 0; j < 4; ++j) {
      bf16x8 bk0 = *(const bf16x8*)&Ks[(j * 16 + l16) * SD + quad * 8];
      bf16x8 bk1 = *(const bf16x8*)&Ks[(j * 16 + l16) * SD + 32 + quad * 8];
#pragma unroll
      for (int i = 0; i < 2; ++i) {
        S[i][j] = __builtin_amdgcn_mfma_f32_16x16x32_bf16(aq[i][0], bk0, S[i][j], 0, 0, 0);
        S[i][j] = __builtin_amdgcn_mfma_f32_16x16x32_bf16(aq[i][1], bk1, S[i][j], 0, 0, 0);
      }
    }

    bool needMask = (kt >= 2 * qt);
#pragma unroll
    for (int i = 0; i < 2; ++i) {
#pragma unroll
      for (int r = 0; r < 4; ++r) {
        int rl = wq + i * 16 + quad * 4 + r;
        float mx = NEG_BIG;
#pragma unroll
        for (int j = 0; j < 4; ++j) {
          float sv = S[i][j][r] * 0.125f;
          if (needMask && (kt * 64 + j * 16 + l16 > q0 + rl)) sv = NEG_BIG;
          S[i][j][r] = sv;
          mx = fmaxf(mx, sv);
        }
        mx = fmaxf(mx, __shfl_xor(mx, 1));
        mx = fmaxf(mx, __shfl_xor(mx, 2));
        mx = fmaxf(mx, __shfl_xor(mx, 4));
        mx = fmaxf(mx, __shfl_xor(mx, 8));
        float mn = fmaxf(m_i[i][r], mx);
        float alpha = __expf(m_i[i][r] - mn);
        m_i[i][r] = mn;
        float sum = 0.f;
#pragma unroll
        for (int j = 0; j < 4; ++j) {
          float p = __expf(S[i][j][r] - mn);
          PQ[rl * SD + j * 16 + l16] = f2b(p);
          sum += p;
        }
        sum += __shfl_xor(sum, 1);
        sum += __shfl_xor(sum, 2);
        sum += __shfl_xor(sum, 4);
        sum += __shfl_xor(sum, 8);
        l_i[i][r] = alpha * l_i[i][r] + sum;
#pragma unroll
        for (int jd = 0; jd < 4; ++jd) Oacc[i][jd][r] *= alpha;
      }
    }
    __syncthreads();

#pragma unroll
    for (int ks = 0; ks < 2; ++ks) {
      bf16x8 ap[2];
#pragma unroll
      for (int i = 0; i < 2; ++i)
        ap[i] = *(const bf16x8*)&PQ[(wq + i * 16 + l16) * SD + ks * 32 + quad * 8];
#pragma unroll
      for (int jd = 0; jd < 4; ++jd) {
        bf16x8 bv;
#pragma unroll
        for (int jj = 0; jj < 8; ++jj)
          bv[jj] = (short)Vs[(ks * 32 + quad * 8 + jj) * SD + jd * 16 + l16];
#pragma unroll
        for (int i = 0; i < 2; ++i)
          Oacc[i][jd] = __builtin_amdgcn_mfma_f32_16x16x32_bf16(ap[i], bv, Oacc[i][jd], 0, 0, 0);
      }
    }
    __syncthreads();
  }

#pragma unroll
  for (int i = 0; i < 2; ++i)
#pragma unroll
    for (int jd = 0; jd < 4; ++jd)
#pragma unroll
      for (int r = 0; r < 4; ++r) {
        float v = Oacc[i][jd][r] / l_i[i][r];
        size_t row = (size_t)b * 2048 + q0 + wq + i * 16 + quad * 4 + r;
        out[row * 1024 + h * 64 + jd * 16 + l16] = f2b(v);
      }
}

// ---------------------------------------------------------------------------
extern "C" void kernel_launch(void* const* d_in, const int* in_sizes, int n_in,
                              void* d_out, int out_size, void* d_ws, size_t ws_size,
                              hipStream_t stream) {
  (void)in_sizes; (void)n_in; (void)out_size; (void)ws_size;
  const void* x     = d_in[0];
  const void* ln1s  = d_in[2];
  const void* ln1b  = d_in[3];
  const void* ln2s  = d_in[4];
  const void* ln2b  = d_in[5];
  const void* w_qkv = d_in[6];
  const void* b_qkv = d_in[7];
  const void* w_ap  = d_in[8];
  const void* b_ap  = d_in[9];
  const void* w_fc  = d_in[10];
  const void* b_fc  = d_in[11];
  const void* w_mp  = d_in[12];
  const void* b_mp  = d_in[13];
  char* ws = (char*)d_ws;

  const int M = 4096, D = 1024, DFF = 4096, QKV3 = 3072;
  size_t off = 0;
  auto alloc = [&](size_t n) { char* p = ws + off; off += n; return p; };
  int* flag            = (int*)alloc(256);
  unsigned short* wT   = (unsigned short*)alloc((size_t)DFF * D * 2);  // 8 MiB
  unsigned short* hbuf = (unsigned short*)alloc((size_t)M * D * 2);    // 8 MiB
  unsigned short* x1   = (unsigned short*)alloc((size_t)M * D * 2);    // 8 MiB
  char* region = alloc((size_t)M * DFF * 2);                            // 32 MiB
  unsigned short* qkvb = (unsigned short*)region;                       // [4096][3072]
  unsigned short* attn = (unsigned short*)(region + (size_t)M * QKV3 * 2); // [4096][1024]
  unsigned short* fcb  = (unsigned short*)region;                       // [4096][4096]

  dim3 blk(256);
  detect_k<<<dim3(1), dim3(64), 0, stream>>>((const unsigned short*)x, flag);
  transpose_k<<<dim3(QKV3 / 64, D / 64), blk, 0, stream>>>(w_qkv, wT, D, QKV3, flag);
  ln_k<<<dim3(M), blk, 0, stream>>>(x, ln1s, ln1b, hbuf, flag, 1);
  gemm_bt<0><<<dim3(QKV3 / 128, M / 128), blk, 0, stream>>>(hbuf, wT, b_qkv, nullptr, qkvb, M, QKV3, D, flag, 0, 0);
  attn_k<<<dim3(16, 32), blk, 0, stream>>>(qkvb, attn);
  transpose_k<<<dim3(D / 64, D / 64), blk, 0, stream>>>(w_ap, wT, D, D, flag);
  gemm_bt<2><<<dim3(D / 128, M / 128), blk, 0, stream>>>(attn, wT, b_ap, x, x1, M, D, D, flag, 1, 0);
  transpose_k<<<dim3(DFF / 64, D / 64), blk, 0, stream>>>(w_fc, wT, D, DFF, flag);
  ln_k<<<dim3(M), blk, 0, stream>>>(x1, ln2s, ln2b, hbuf, flag, 0);
  gemm_bt<1><<<dim3(DFF / 128, M / 128), blk, 0, stream>>>(hbuf, wT, b_fc, nullptr, fcb, M, DFF, D, flag, 0, 0);
  transpose_k<<<dim3(D / 64, DFF / 64), blk, 0, stream>>>(w_mp, wT, DFF, D, flag);
  gemm_bt<2><<<dim3(D / 128, M / 128), blk, 0, stream>>>(fcb, wT, b_mp, x1, d_out, M, D, DFF, flag, 0, 1);
}

// Round 4
// 482.303 us; speedup vs baseline: 1.2917x; 1.2917x over previous
//
#include <hip/hip_runtime.h>
#include <stdint.h>

// ---------------------------------------------------------------------------
// GPT-2 block, runtime dtype-adaptive (fp32 or bf16 external), bf16 internal,
// fp32 accumulate. MI355X / gfx950.
// R4: S^T-layout flash attention (reg softmax, vectorized P/V LDS paths,
// paired q-tiles for balance) + m97 global_load_lds GEMM staging + TN=64
// tiles for N=1024 GEMMs.
// ---------------------------------------------------------------------------

typedef __attribute__((ext_vector_type(8))) short bf16x8;
typedef __attribute__((ext_vector_type(8))) unsigned short u16x8;
typedef __attribute__((ext_vector_type(4))) float f32x4;

#define NEG_BIG -30000.0f
#define EXP2SC 0.18033688011112042f   // 0.125 * log2(e)

__device__ __forceinline__ float b2f(unsigned short u) {
  union { unsigned int i; float f; } c; c.i = ((unsigned int)u) << 16; return c.f;
}
__device__ __forceinline__ unsigned short f2b(float f) {
  union { float f; unsigned int u; } c; c.f = f;
  unsigned int r = c.u + 0x7fffu + ((c.u >> 16) & 1u);   // RNE
  return (unsigned short)(r >> 16);
}
__device__ __forceinline__ float ldx(const void* p, size_t i, int f32) {
  return f32 ? ((const float*)p)[i] : b2f(((const unsigned short*)p)[i]);
}
__device__ __forceinline__ void gld_lds16(const void* g, void* l) {
  __builtin_amdgcn_global_load_lds(
      (__attribute__((address_space(1))) void*)(void*)g,
      (__attribute__((address_space(3))) void*)l, 16, 0, 0);
}

// ---------------------------------------------------------------------------
__global__ void detect_k(const unsigned short* __restrict__ x, int* __restrict__ flag) {
  int lane = threadIdx.x;
  int cnt = 0;
#pragma unroll
  for (int j = 0; j < 4; ++j) {
    unsigned e = (x[lane * 4 + j] >> 7) & 0xFF;
    if (e >= 100 && e <= 145) cnt++;
  }
#pragma unroll
  for (int off = 32; off; off >>= 1) cnt += __shfl_down(cnt, off);
  if (lane == 0) *flag = (cnt < 220) ? 1 : 0;
}

// ---------------------------------------------------------------------------
// 64x64 tile transpose, adaptive input, bf16 out: out[n*K+k] = in[k*N+n]
// ---------------------------------------------------------------------------
__global__ __launch_bounds__(256) void transpose_k(
    const void* __restrict__ in, unsigned short* __restrict__ out,
    int K, int N, const int* __restrict__ flag) {
  int fm = *flag;
  __shared__ unsigned short tile[64][72];
  int n0 = blockIdx.x * 64, k0 = blockIdx.y * 64;
  int t = threadIdx.x;
  int r = t >> 3, c0 = (t & 7) * 8;
#pragma unroll
  for (int p = 0; p < 2; ++p) {
    int k = r + p * 32;
#pragma unroll
    for (int j = 0; j < 8; ++j)
      tile[k][c0 + j] = f2b(ldx(in, (size_t)(k0 + k) * N + n0 + c0 + j, fm));
  }
  __syncthreads();
#pragma unroll
  for (int p = 0; p < 2; ++p) {
    int n = r + p * 32;
    u16x8 v;
#pragma unroll
    for (int j = 0; j < 8; ++j) v[j] = tile[c0 + j][n];
    *(u16x8*)(out + (size_t)(n0 + n) * K + k0 + c0) = v;
  }
}

// ---------------------------------------------------------------------------
// LayerNorm D=1024
// ---------------------------------------------------------------------------
__global__ __launch_bounds__(256) void ln_k(
    const void* __restrict__ x, const void* __restrict__ sc,
    const void* __restrict__ bs, unsigned short* __restrict__ out,
    const int* __restrict__ flag, int xAdap) {
  int fm = *flag;
  int fx = xAdap ? fm : 0;
  int row = blockIdx.x, t = threadIdx.x;
  size_t base = (size_t)row * 1024 + t * 4;
  float f0 = ldx(x, base, fx), f1 = ldx(x, base + 1, fx);
  float f2 = ldx(x, base + 2, fx), f3 = ldx(x, base + 3, fx);
  float s = f0 + f1 + f2 + f3;
  float q = f0 * f0 + f1 * f1 + f2 * f2 + f3 * f3;
#pragma unroll
  for (int off = 32; off; off >>= 1) {
    s += __shfl_down(s, off);
    q += __shfl_down(q, off);
  }
  __shared__ float red[8];
  int w = t >> 6, lane = t & 63;
  if (lane == 0) { red[w] = s; red[w + 4] = q; }
  __syncthreads();
  float S = red[0] + red[1] + red[2] + red[3];
  float Q = red[4] + red[5] + red[6] + red[7];
  float mean = S * (1.f / 1024.f);
  float var = Q * (1.f / 1024.f) - mean * mean;
  float rstd = rsqrtf(var + 1e-5f);
  int c = t * 4;
  ushort4 o;
  o.x = f2b((f0 - mean) * rstd * ldx(sc, c, fm)     + ldx(bs, c, fm));
  o.y = f2b((f1 - mean) * rstd * ldx(sc, c + 1, fm) + ldx(bs, c + 1, fm));
  o.z = f2b((f2 - mean) * rstd * ldx(sc, c + 2, fm) + ldx(bs, c + 2, fm));
  o.w = f2b((f3 - mean) * rstd * ldx(sc, c + 3, fm) + ldx(bs, c + 3, fm));
  ((ushort4*)(out + (size_t)row * 1024))[t] = o;
}

// ---------------------------------------------------------------------------
// GEMM: C[M,N] = A[M,K]*Bt[N,K]^T + bias; EPI: 0=none 1=gelu 2=+res
// 128xTN tile, BK=32, 4 waves, global_load_lds width=16 (m97 structure).
// ---------------------------------------------------------------------------
template <int EPI, int TN>
__global__ __launch_bounds__(256) void gemm_bt(
    const unsigned short* __restrict__ A, const unsigned short* __restrict__ Bt,
    const void* __restrict__ bias, const void* __restrict__ res,
    void* __restrict__ C, int M, int N, int K,
    const int* __restrict__ flag, int resAdap, int outAdap) {
  constexpr int JW = TN / 32;            // n-frags per wave
  int fm = *flag;
  int fr = resAdap ? fm : 0;
  int fo = outAdap ? fm : 0;
  __shared__ unsigned short As[128 * 32];
  __shared__ unsigned short Bs[TN * 32];
  int t = threadIdx.x;
  int bn = blockIdx.x * TN, bm = blockIdx.y * 128;
  int w = t >> 6, lane = t & 63, quad = lane >> 4, l16 = lane & 15;
  int wm = (w >> 1) * 64, wn = (w & 1) * (TN / 2);
  f32x4 acc[4][JW] = {};

  int c1 = t, c2 = t + 256;
  int r1 = c1 >> 2, e1 = (c1 & 3) * 8;
  int r2 = c2 >> 2, e2 = (c2 & 3) * 8;
  const unsigned short* a1 = A + (size_t)(bm + r1) * K + e1;
  const unsigned short* a2 = A + (size_t)(bm + r2) * K + e2;
  const unsigned short* b1 = Bt + (size_t)(bn + r1) * K + e1;
  const unsigned short* b2 = Bt + (size_t)(bn + (TN == 128 ? r2 : 0)) * K + e2;

  for (int k0 = 0; k0 < K; k0 += 32) {
    gld_lds16(a1 + k0, As + c1 * 8);
    gld_lds16(a2 + k0, As + c2 * 8);
    gld_lds16(b1 + k0, Bs + c1 * 8);
    if (TN == 128) gld_lds16(b2 + k0, Bs + c2 * 8);
    __syncthreads();
    bf16x8 af[4], bfr[JW];
#pragma unroll
    for (int i = 0; i < 4; ++i)
      af[i] = *(const bf16x8*)&As[(wm + i * 16 + l16) * 32 + quad * 8];
#pragma unroll
    for (int j = 0; j < JW; ++j)
      bfr[j] = *(const bf16x8*)&Bs[(wn + j * 16 + l16) * 32 + quad * 8];
#pragma unroll
    for (int i = 0; i < 4; ++i)
#pragma unroll
      for (int j = 0; j < JW; ++j)
        acc[i][j] = __builtin_amdgcn_mfma_f32_16x16x32_bf16(af[i], bfr[j], acc[i][j], 0, 0, 0);
    __syncthreads();
  }

#pragma unroll
  for (int j = 0; j < JW; ++j) {
    int col = bn + wn + j * 16 + l16;
    float bb = ldx(bias, col, fm);
#pragma unroll
    for (int i = 0; i < 4; ++i) {
      int row0 = bm + wm + i * 16 + quad * 4;
#pragma unroll
      for (int r = 0; r < 4; ++r) {
        float v = acc[i][j][r] + bb;
        if (EPI == 1) {
          float u = 0.7978845608f * (v + 0.044715f * v * v * v);
          float e = __expf(2.f * u);          // tanh(u) = 1 - 2/(e^{2u}+1)
          float th = 1.f - 2.f / (e + 1.f);
          v = 0.5f * v * (1.f + th);
        } else if (EPI == 2) {
          v += ldx(res, (size_t)(row0 + r) * N + col, fr);
        }
        size_t idx = (size_t)(row0 + r) * N + col;
        if (fo) ((float*)C)[idx] = v;
        else    ((unsigned short*)C)[idx] = f2b(v);
      }
    }
  }
}

// ---------------------------------------------------------------------------
// Flash attention v2, causal, S^T formulation.
// Block: pair of 64-row q-tiles (pi, 31-pi) -> 33 kt-iters per block (balanced).
// 4 waves x 16 q-rows. qkv [4096][3072] bf16 (ws), out [4096][1024] bf16.
// Layouts:
//   Ks[s][d]  : 64 x 64, row stride 72 ushorts (b128-aligned A-frags)
//   Vt[d][s]  : 64 x 64 transposed, dword-packed, row stride 35 dwords
//   Ps[q][s]  : per-wave 16 x 64, row stride 72 ushorts
// S^T = K·Q^T: lane holds col q=l16, rows s=i*16+quad*4+r -> softmax is
// per-lane regs + 2 shfl. P written 4x ds_write_b64, read 2x ds_read_b128
// (same wave, no barrier). O = P·V: C-layout row q=quad*4+r, col d=jd*16+l16.
// ---------------------------------------------------------------------------
__global__ __launch_bounds__(256) void attn_k(
    const unsigned short* __restrict__ qkv, unsigned short* __restrict__ out) {
  __shared__ unsigned short Ks[64 * 72];
  __shared__ unsigned int   Vt[64 * 35];
  __shared__ unsigned short Ps[4 * 16 * 72];
  int t = threadIdx.x, w = t >> 6, lane = t & 63, quad = lane >> 4, l16 = lane & 15;
  int pi = blockIdx.x, bh = blockIdx.y, b = bh >> 4, h = bh & 15;
  const unsigned short* base = qkv + (size_t)b * 2048 * 3072 + h * 64;
  unsigned short* Pw = Ps + w * 16 * 72;
  int srow = t >> 3, d0 = (t & 7) * 8;       // staging coords

#pragma unroll 1
  for (int half = 0; half < 2; ++half) {
    int qt = half ? (31 - pi) : pi;
    int q0 = qt * 64;
    int qrel = w * 16 + l16;
    const unsigned short* qp = base + (size_t)(q0 + qrel) * 3072;
    bf16x8 bq0 = *(const bf16x8*)(qp + quad * 8);
    bf16x8 bq1 = *(const bf16x8*)(qp + 32 + quad * 8);
    float m_i = NEG_BIG, l_i = 0.f;
    f32x4 O[4] = {};

#pragma unroll 1
    for (int kt = 0; kt <= qt; ++kt) {
      const unsigned short* kb = base + (size_t)(kt * 64) * 3072;
      // --- stage K [64][64] -> Ks (stride 72) ---
      {
        u16x8 k0v = *(const u16x8*)(kb + (size_t)srow * 3072 + 1024 + d0);
        u16x8 k1v = *(const u16x8*)(kb + (size_t)(srow + 32) * 3072 + 1024 + d0);
        *(u16x8*)&Ks[srow * 72 + d0] = k0v;
        *(u16x8*)&Ks[(srow + 32) * 72 + d0] = k1v;
        // --- stage V transposed: Vt[d][s], dword-packed pairs ---
        int sp = t >> 3;                      // s-pair 0..31
        u16x8 va = *(const u16x8*)(kb + (size_t)(2 * sp) * 3072 + 2048 + d0);
        u16x8 vb = *(const u16x8*)(kb + (size_t)(2 * sp + 1) * 3072 + 2048 + d0);
#pragma unroll
        for (int j = 0; j < 8; ++j)
          Vt[(d0 + j) * 35 + sp] = (unsigned int)va[j] | ((unsigned int)vb[j] << 16);
      }
      __syncthreads();

      // --- S^T = K · Q^T : per wave [64 s][16 q] ---
      f32x4 ST[4];
#pragma unroll
      for (int i = 0; i < 4; ++i) {
        bf16x8 ak0 = *(const bf16x8*)&Ks[(i * 16 + l16) * 72 + quad * 8];
        bf16x8 ak1 = *(const bf16x8*)&Ks[(i * 16 + l16) * 72 + 32 + quad * 8];
        f32x4 z = {};
        z = __builtin_amdgcn_mfma_f32_16x16x32_bf16(ak0, bq0, z, 0, 0, 0);
        ST[i] = __builtin_amdgcn_mfma_f32_16x16x32_bf16(ak1, bq1, z, 0, 0, 0);
      }

      // --- online softmax (exp2 domain), per-lane regs + cross-quad shfl ---
      bool dm = (kt == qt);
      float p[4][4];
      float mx = NEG_BIG;
#pragma unroll
      for (int i = 0; i < 4; ++i)
#pragma unroll
        for (int r = 0; r < 4; ++r) {
          float v = ST[i][r] * EXP2SC;
          int srel = i * 16 + quad * 4 + r;
          if (dm && srel > qrel) v = NEG_BIG;
          p[i][r] = v;
          mx = fmaxf(mx, v);
        }
      mx = fmaxf(mx, __shfl_xor(mx, 16));
      mx = fmaxf(mx, __shfl_xor(mx, 32));
      float mn = fmaxf(m_i, mx);
      float alpha = exp2f(m_i - mn);
      m_i = mn;
      float sum = 0.f;
#pragma unroll
      for (int i = 0; i < 4; ++i)
#pragma unroll
        for (int r = 0; r < 4; ++r) {
          float e = exp2f(p[i][r] - mn);
          p[i][r] = e;
          sum += e;
        }
      sum += __shfl_xor(sum, 16);
      sum += __shfl_xor(sum, 32);
      l_i = alpha * l_i + sum;

      // --- write P[q=l16][s] : 4x ds_write_b64, same-wave region ---
#pragma unroll
      for (int i = 0; i < 4; ++i) {
        uint2 pr;
        pr.x = (unsigned int)f2b(p[i][0]) | ((unsigned int)f2b(p[i][1]) << 16);
        pr.y = (unsigned int)f2b(p[i][2]) | ((unsigned int)f2b(p[i][3]) << 16);
        *(uint2*)(Pw + l16 * 72 + i * 16 + quad * 4) = pr;
      }

      // --- rescale O (alpha broadcast from col-owner lane to row-owner) ---
      float ar[4];
#pragma unroll
      for (int r = 0; r < 4; ++r)
        ar[r] = __shfl(alpha, (lane & 48) | (quad * 4 + r));
#pragma unroll
      for (int jd = 0; jd < 4; ++jd)
#pragma unroll
        for (int r = 0; r < 4; ++r) O[jd][r] *= ar[r];

      // --- O += P · V ---
#pragma unroll
      for (int ks = 0; ks < 2; ++ks) {
        bf16x8 ap = *(const bf16x8*)(Pw + l16 * 72 + ks * 32 + quad * 8);
#pragma unroll
        for (int jd = 0; jd < 4; ++jd) {
          union { unsigned int u[4]; bf16x8 v; } bv;
          int vbase = (jd * 16 + l16) * 35 + ks * 16 + quad * 4;
#pragma unroll
          for (int cc = 0; cc < 4; ++cc) bv.u[cc] = Vt[vbase + cc];
          O[jd] = __builtin_amdgcn_mfma_f32_16x16x32_bf16(ap, bv.v, O[jd], 0, 0, 0);
        }
      }
      __syncthreads();   // Ks/Vt consumed before restage
    }

    // --- epilogue: O rows q=quad*4+r, cols d=jd*16+l16 ---
    float li[4];
#pragma unroll
    for (int r = 0; r < 4; ++r)
      li[r] = 1.f / __shfl(l_i, (lane & 48) | (quad * 4 + r));
#pragma unroll
    for (int jd = 0; jd < 4; ++jd)
#pragma unroll
      for (int r = 0; r < 4; ++r) {
        size_t row = (size_t)b * 2048 + q0 + w * 16 + quad * 4 + r;
        out[row * 1024 + h * 64 + jd * 16 + l16] = f2b(O[jd][r] * li[r]);
      }
  }
}

// ---------------------------------------------------------------------------
extern "C" void kernel_launch(void* const* d_in, const int* in_sizes, int n_in,
                              void* d_out, int out_size, void* d_ws, size_t ws_size,
                              hipStream_t stream) {
  (void)in_sizes; (void)n_in; (void)out_size; (void)ws_size;
  const void* x     = d_in[0];
  const void* ln1s  = d_in[2];
  const void* ln1b  = d_in[3];
  const void* ln2s  = d_in[4];
  const void* ln2b  = d_in[5];
  const void* w_qkv = d_in[6];
  const void* b_qkv = d_in[7];
  const void* w_ap  = d_in[8];
  const void* b_ap  = d_in[9];
  const void* w_fc  = d_in[10];
  const void* b_fc  = d_in[11];
  const void* w_mp  = d_in[12];
  const void* b_mp  = d_in[13];
  char* ws = (char*)d_ws;

  const int M = 4096, D = 1024, DFF = 4096, QKV3 = 3072;
  size_t off = 0;
  auto alloc = [&](size_t n) { char* p = ws + off; off += n; return p; };
  int* flag            = (int*)alloc(256);
  unsigned short* wT   = (unsigned short*)alloc((size_t)DFF * D * 2);
  unsigned short* hbuf = (unsigned short*)alloc((size_t)M * D * 2);
  unsigned short* x1   = (unsigned short*)alloc((size_t)M * D * 2);
  char* region = alloc((size_t)M * DFF * 2);
  unsigned short* qkvb = (unsigned short*)region;                          // [4096][3072]
  unsigned short* attn = (unsigned short*)(region + (size_t)M * QKV3 * 2); // [4096][1024]
  unsigned short* fcb  = (unsigned short*)region;                          // [4096][4096]

  dim3 blk(256);
  detect_k<<<dim3(1), dim3(64), 0, stream>>>((const unsigned short*)x, flag);
  transpose_k<<<dim3(QKV3 / 64, D / 64), blk, 0, stream>>>(w_qkv, wT, D, QKV3, flag);
  ln_k<<<dim3(M), blk, 0, stream>>>(x, ln1s, ln1b, hbuf, flag, 1);
  gemm_bt<0, 128><<<dim3(QKV3 / 128, M / 128), blk, 0, stream>>>(hbuf, wT, b_qkv, nullptr, qkvb, M, QKV3, D, flag, 0, 0);
  attn_k<<<dim3(16, 32), blk, 0, stream>>>(qkvb, attn);
  transpose_k<<<dim3(D / 64, D / 64), blk, 0, stream>>>(w_ap, wT, D, D, flag);
  gemm_bt<2, 64><<<dim3(D / 64, M / 128), blk, 0, stream>>>(attn, wT, b_ap, x, x1, M, D, D, flag, 1, 0);
  transpose_k<<<dim3(DFF / 64, D / 64), blk, 0, stream>>>(w_fc, wT, D, DFF, flag);
  ln_k<<<dim3(M), blk, 0, stream>>>(x1, ln2s, ln2b, hbuf, flag, 0);
  gemm_bt<1, 128><<<dim3(DFF / 128, M / 128), blk, 0, stream>>>(hbuf, wT, b_fc, nullptr, fcb, M, DFF, D, flag, 0, 0);
  transpose_k<<<dim3(D / 64, DFF / 64), blk, 0, stream>>>(w_mp, wT, DFF, D, flag);
  gemm_bt<2, 64><<<dim3(D / 64, M / 128), blk, 0, stream>>>(fcb, wT, b_mp, x1, d_out, M, D, DFF, flag, 0, 1);
}

// Round 5
// 457.955 us; speedup vs baseline: 1.3604x; 1.0532x over previous
//
#include <hip/hip_runtime.h>
#include <stdint.h>

// ---------------------------------------------------------------------------
// GPT-2 block, runtime dtype-adaptive (fp32 or bf16 external), bf16 internal,
// fp32 accumulate. MI355X / gfx950.
// R5: split-K=2 (fp32 partials + fused reduce) for the N=1024 proj GEMMs,
// all GEMMs on the 128x128 m97 tile; vectorized fp32 transpose/LN loads.
// ---------------------------------------------------------------------------

typedef __attribute__((ext_vector_type(8))) short bf16x8;
typedef __attribute__((ext_vector_type(8))) unsigned short u16x8;
typedef __attribute__((ext_vector_type(4))) float f32x4;

#define NEG_BIG -30000.0f
#define EXP2SC 0.18033688011112042f   // 0.125 * log2(e)

__device__ __forceinline__ float b2f(unsigned short u) {
  union { unsigned int i; float f; } c; c.i = ((unsigned int)u) << 16; return c.f;
}
__device__ __forceinline__ unsigned short f2b(float f) {
  union { float f; unsigned int u; } c; c.f = f;
  unsigned int r = c.u + 0x7fffu + ((c.u >> 16) & 1u);   // RNE
  return (unsigned short)(r >> 16);
}
__device__ __forceinline__ float ldx(const void* p, size_t i, int f32) {
  return f32 ? ((const float*)p)[i] : b2f(((const unsigned short*)p)[i]);
}
__device__ __forceinline__ void gld_lds16(const void* g, void* l) {
  __builtin_amdgcn_global_load_lds(
      (__attribute__((address_space(1))) void*)(void*)g,
      (__attribute__((address_space(3))) void*)l, 16, 0, 0);
}

// ---------------------------------------------------------------------------
__global__ void detect_k(const unsigned short* __restrict__ x, int* __restrict__ flag) {
  int lane = threadIdx.x;
  int cnt = 0;
#pragma unroll
  for (int j = 0; j < 4; ++j) {
    unsigned e = (x[lane * 4 + j] >> 7) & 0xFF;
    if (e >= 100 && e <= 145) cnt++;
  }
#pragma unroll
  for (int off = 32; off; off >>= 1) cnt += __shfl_down(cnt, off);
  if (lane == 0) *flag = (cnt < 220) ? 1 : 0;
}

// ---------------------------------------------------------------------------
// 64x64 tile transpose, adaptive input, bf16 out: out[n*K+k] = in[k*N+n]
// ---------------------------------------------------------------------------
__global__ __launch_bounds__(256) void transpose_k(
    const void* __restrict__ in, unsigned short* __restrict__ out,
    int K, int N, const int* __restrict__ flag) {
  int fm = *flag;
  __shared__ unsigned short tile[64][72];
  int n0 = blockIdx.x * 64, k0 = blockIdx.y * 64;
  int t = threadIdx.x;
  int r = t >> 3, c0 = (t & 7) * 8;
  if (fm) {
    const float* inf = (const float*)in;
#pragma unroll
    for (int p = 0; p < 2; ++p) {
      int k = r + p * 32;
      float4 v0 = *(const float4*)(inf + (size_t)(k0 + k) * N + n0 + c0);
      float4 v1 = *(const float4*)(inf + (size_t)(k0 + k) * N + n0 + c0 + 4);
      tile[k][c0 + 0] = f2b(v0.x); tile[k][c0 + 1] = f2b(v0.y);
      tile[k][c0 + 2] = f2b(v0.z); tile[k][c0 + 3] = f2b(v0.w);
      tile[k][c0 + 4] = f2b(v1.x); tile[k][c0 + 5] = f2b(v1.y);
      tile[k][c0 + 6] = f2b(v1.z); tile[k][c0 + 7] = f2b(v1.w);
    }
  } else {
    const unsigned short* inu = (const unsigned short*)in;
#pragma unroll
    for (int p = 0; p < 2; ++p) {
      int k = r + p * 32;
      u16x8 v = *(const u16x8*)(inu + (size_t)(k0 + k) * N + n0 + c0);
      *(u16x8*)&tile[k][c0] = v;
    }
  }
  __syncthreads();
#pragma unroll
  for (int p = 0; p < 2; ++p) {
    int n = r + p * 32;
    u16x8 v;
#pragma unroll
    for (int j = 0; j < 8; ++j) v[j] = tile[c0 + j][n];
    *(u16x8*)(out + (size_t)(n0 + n) * K + k0 + c0) = v;
  }
}

// ---------------------------------------------------------------------------
// LayerNorm D=1024
// ---------------------------------------------------------------------------
__global__ __launch_bounds__(256) void ln_k(
    const void* __restrict__ x, const void* __restrict__ sc,
    const void* __restrict__ bs, unsigned short* __restrict__ out,
    const int* __restrict__ flag, int xAdap) {
  int fm = *flag;
  int fx = xAdap ? fm : 0;
  int row = blockIdx.x, t = threadIdx.x;
  float f0, f1, f2, f3;
  if (fx) {
    float4 xv = ((const float4*)x)[(size_t)row * 256 + t];
    f0 = xv.x; f1 = xv.y; f2 = xv.z; f3 = xv.w;
  } else {
    ushort4 xv = ((const ushort4*)x)[(size_t)row * 256 + t];
    f0 = b2f(xv.x); f1 = b2f(xv.y); f2 = b2f(xv.z); f3 = b2f(xv.w);
  }
  float s = f0 + f1 + f2 + f3;
  float q = f0 * f0 + f1 * f1 + f2 * f2 + f3 * f3;
#pragma unroll
  for (int off = 32; off; off >>= 1) {
    s += __shfl_down(s, off);
    q += __shfl_down(q, off);
  }
  __shared__ float red[8];
  int w = t >> 6, lane = t & 63;
  if (lane == 0) { red[w] = s; red[w + 4] = q; }
  __syncthreads();
  float S = red[0] + red[1] + red[2] + red[3];
  float Q = red[4] + red[5] + red[6] + red[7];
  float mean = S * (1.f / 1024.f);
  float var = Q * (1.f / 1024.f) - mean * mean;
  float rstd = rsqrtf(var + 1e-5f);
  int c = t * 4;
  ushort4 o;
  o.x = f2b((f0 - mean) * rstd * ldx(sc, c, fm)     + ldx(bs, c, fm));
  o.y = f2b((f1 - mean) * rstd * ldx(sc, c + 1, fm) + ldx(bs, c + 1, fm));
  o.z = f2b((f2 - mean) * rstd * ldx(sc, c + 2, fm) + ldx(bs, c + 2, fm));
  o.w = f2b((f3 - mean) * rstd * ldx(sc, c + 3, fm) + ldx(bs, c + 3, fm));
  ((ushort4*)(out + (size_t)row * 1024))[t] = o;
}

// ---------------------------------------------------------------------------
// GEMM: C[M,N] = A[M,K]*Bt[N,K]^T + bias; EPI: 0=none 1=gelu 2=+res
// 128x128 tile, BK=32, 4 waves, global_load_lds width=16 (m97 structure).
// ---------------------------------------------------------------------------
template <int EPI>
__global__ __launch_bounds__(256) void gemm_bt(
    const unsigned short* __restrict__ A, const unsigned short* __restrict__ Bt,
    const void* __restrict__ bias, const void* __restrict__ res,
    void* __restrict__ C, int M, int N, int K,
    const int* __restrict__ flag, int resAdap, int outAdap) {
  int fm = *flag;
  int fr = resAdap ? fm : 0;
  int fo = outAdap ? fm : 0;
  __shared__ unsigned short As[128 * 32];
  __shared__ unsigned short Bs[128 * 32];
  int t = threadIdx.x;
  int bn = blockIdx.x * 128, bm = blockIdx.y * 128;
  int w = t >> 6, lane = t & 63, quad = lane >> 4, l16 = lane & 15;
  int wm = (w >> 1) * 64, wn = (w & 1) * 64;
  f32x4 acc[4][4] = {};

  int c1 = t, c2 = t + 256;
  int r1 = c1 >> 2, e1 = (c1 & 3) * 8;
  int r2 = c2 >> 2, e2 = (c2 & 3) * 8;
  const unsigned short* a1 = A + (size_t)(bm + r1) * K + e1;
  const unsigned short* a2 = A + (size_t)(bm + r2) * K + e2;
  const unsigned short* b1 = Bt + (size_t)(bn + r1) * K + e1;
  const unsigned short* b2 = Bt + (size_t)(bn + r2) * K + e2;

  for (int k0 = 0; k0 < K; k0 += 32) {
    gld_lds16(a1 + k0, As + c1 * 8);
    gld_lds16(a2 + k0, As + c2 * 8);
    gld_lds16(b1 + k0, Bs + c1 * 8);
    gld_lds16(b2 + k0, Bs + c2 * 8);
    __syncthreads();
    bf16x8 af[4], bfr[4];
#pragma unroll
    for (int i = 0; i < 4; ++i)
      af[i] = *(const bf16x8*)&As[(wm + i * 16 + l16) * 32 + quad * 8];
#pragma unroll
    for (int j = 0; j < 4; ++j)
      bfr[j] = *(const bf16x8*)&Bs[(wn + j * 16 + l16) * 32 + quad * 8];
#pragma unroll
    for (int i = 0; i < 4; ++i)
#pragma unroll
      for (int j = 0; j < 4; ++j)
        acc[i][j] = __builtin_amdgcn_mfma_f32_16x16x32_bf16(af[i], bfr[j], acc[i][j], 0, 0, 0);
    __syncthreads();
  }

#pragma unroll
  for (int j = 0; j < 4; ++j) {
    int col = bn + wn + j * 16 + l16;
    float bb = ldx(bias, col, fm);
#pragma unroll
    for (int i = 0; i < 4; ++i) {
      int row0 = bm + wm + i * 16 + quad * 4;
#pragma unroll
      for (int r = 0; r < 4; ++r) {
        float v = acc[i][j][r] + bb;
        if (EPI == 1) {
          float u = 0.7978845608f * (v + 0.044715f * v * v * v);
          float e = __expf(2.f * u);          // tanh(u) = 1 - 2/(e^{2u}+1)
          float th = 1.f - 2.f / (e + 1.f);
          v = 0.5f * v * (1.f + th);
        } else if (EPI == 2) {
          v += ldx(res, (size_t)(row0 + r) * N + col, fr);
        }
        size_t idx = (size_t)(row0 + r) * N + col;
        if (fo) ((float*)C)[idx] = v;
        else    ((unsigned short*)C)[idx] = f2b(v);
      }
    }
  }
}

// ---------------------------------------------------------------------------
// Split-K GEMM: P[z][M,N] = A[:, z*Kh:(z+1)*Kh] * Bt^T (fp32, no epilogue)
// ---------------------------------------------------------------------------
__global__ __launch_bounds__(256) void gemm_pk(
    const unsigned short* __restrict__ A, const unsigned short* __restrict__ Bt,
    float* __restrict__ P, int M, int N, int Kh, int Kfull) {
  __shared__ unsigned short As[128 * 32];
  __shared__ unsigned short Bs[128 * 32];
  int t = threadIdx.x;
  int bn = blockIdx.x * 128, bm = blockIdx.y * 128;
  int koff = blockIdx.z * Kh;
  float* Pz = P + (size_t)blockIdx.z * M * N;
  int w = t >> 6, lane = t & 63, quad = lane >> 4, l16 = lane & 15;
  int wm = (w >> 1) * 64, wn = (w & 1) * 64;
  f32x4 acc[4][4] = {};

  int c1 = t, c2 = t + 256;
  int r1 = c1 >> 2, e1 = (c1 & 3) * 8;
  int r2 = c2 >> 2, e2 = (c2 & 3) * 8;
  const unsigned short* a1 = A + (size_t)(bm + r1) * Kfull + koff + e1;
  const unsigned short* a2 = A + (size_t)(bm + r2) * Kfull + koff + e2;
  const unsigned short* b1 = Bt + (size_t)(bn + r1) * Kfull + koff + e1;
  const unsigned short* b2 = Bt + (size_t)(bn + r2) * Kfull + koff + e2;

  for (int k0 = 0; k0 < Kh; k0 += 32) {
    gld_lds16(a1 + k0, As + c1 * 8);
    gld_lds16(a2 + k0, As + c2 * 8);
    gld_lds16(b1 + k0, Bs + c1 * 8);
    gld_lds16(b2 + k0, Bs + c2 * 8);
    __syncthreads();
    bf16x8 af[4], bfr[4];
#pragma unroll
    for (int i = 0; i < 4; ++i)
      af[i] = *(const bf16x8*)&As[(wm + i * 16 + l16) * 32 + quad * 8];
#pragma unroll
    for (int j = 0; j < 4; ++j)
      bfr[j] = *(const bf16x8*)&Bs[(wn + j * 16 + l16) * 32 + quad * 8];
#pragma unroll
    for (int i = 0; i < 4; ++i)
#pragma unroll
      for (int j = 0; j < 4; ++j)
        acc[i][j] = __builtin_amdgcn_mfma_f32_16x16x32_bf16(af[i], bfr[j], acc[i][j], 0, 0, 0);
    __syncthreads();
  }

#pragma unroll
  for (int j = 0; j < 4; ++j) {
    int col = bn + wn + j * 16 + l16;
#pragma unroll
    for (int i = 0; i < 4; ++i) {
      int row0 = bm + wm + i * 16 + quad * 4;
#pragma unroll
      for (int r = 0; r < 4; ++r)
        Pz[(size_t)(row0 + r) * N + col] = acc[i][j][r];
    }
  }
}

// ---------------------------------------------------------------------------
// reduce: out = P0 + P1 + bias (+ res), N must be power of two
// ---------------------------------------------------------------------------
__global__ __launch_bounds__(256) void reduce2_k(
    const float* __restrict__ P0, const float* __restrict__ P1,
    const void* __restrict__ bias, const void* __restrict__ res,
    void* __restrict__ out, int N,
    const int* __restrict__ flag, int resAdap, int outAdap) {
  int fm = *flag;
  int fr = resAdap ? fm : 0;
  int fo = outAdap ? fm : 0;
  size_t idx = ((size_t)blockIdx.x * 256 + threadIdx.x) * 4;
  float4 p0 = *(const float4*)(P0 + idx);
  float4 p1 = *(const float4*)(P1 + idx);
  int col = (int)(idx & (size_t)(N - 1));
  float v0 = p0.x + p1.x + ldx(bias, col, fm)     + ldx(res, idx, fr);
  float v1 = p0.y + p1.y + ldx(bias, col + 1, fm) + ldx(res, idx + 1, fr);
  float v2 = p0.z + p1.z + ldx(bias, col + 2, fm) + ldx(res, idx + 2, fr);
  float v3 = p0.w + p1.w + ldx(bias, col + 3, fm) + ldx(res, idx + 3, fr);
  if (fo) {
    float4 o; o.x = v0; o.y = v1; o.z = v2; o.w = v3;
    *(float4*)((float*)out + idx) = o;
  } else {
    ushort4 o; o.x = f2b(v0); o.y = f2b(v1); o.z = f2b(v2); o.w = f2b(v3);
    *(ushort4*)((unsigned short*)out + idx) = o;
  }
}

// ---------------------------------------------------------------------------
// Flash attention v2, causal, S^T formulation (see R4 notes).
// ---------------------------------------------------------------------------
__global__ __launch_bounds__(256) void attn_k(
    const unsigned short* __restrict__ qkv, unsigned short* __restrict__ out) {
  __shared__ unsigned short Ks[64 * 72];
  __shared__ unsigned int   Vt[64 * 35];
  __shared__ unsigned short Ps[4 * 16 * 72];
  int t = threadIdx.x, w = t >> 6, lane = t & 63, quad = lane >> 4, l16 = lane & 15;
  int pi = blockIdx.x, bh = blockIdx.y, b = bh >> 4, h = bh & 15;
  const unsigned short* base = qkv + (size_t)b * 2048 * 3072 + h * 64;
  unsigned short* Pw = Ps + w * 16 * 72;
  int srow = t >> 3, d0 = (t & 7) * 8;

#pragma unroll 1
  for (int half = 0; half < 2; ++half) {
    int qt = half ? (31 - pi) : pi;
    int q0 = qt * 64;
    int qrel = w * 16 + l16;
    const unsigned short* qp = base + (size_t)(q0 + qrel) * 3072;
    bf16x8 bq0 = *(const bf16x8*)(qp + quad * 8);
    bf16x8 bq1 = *(const bf16x8*)(qp + 32 + quad * 8);
    float m_i = NEG_BIG, l_i = 0.f;
    f32x4 O[4] = {};

#pragma unroll 1
    for (int kt = 0; kt <= qt; ++kt) {
      const unsigned short* kb = base + (size_t)(kt * 64) * 3072;
      {
        u16x8 k0v = *(const u16x8*)(kb + (size_t)srow * 3072 + 1024 + d0);
        u16x8 k1v = *(const u16x8*)(kb + (size_t)(srow + 32) * 3072 + 1024 + d0);
        *(u16x8*)&Ks[srow * 72 + d0] = k0v;
        *(u16x8*)&Ks[(srow + 32) * 72 + d0] = k1v;
        int sp = t >> 3;
        u16x8 va = *(const u16x8*)(kb + (size_t)(2 * sp) * 3072 + 2048 + d0);
        u16x8 vb = *(const u16x8*)(kb + (size_t)(2 * sp + 1) * 3072 + 2048 + d0);
#pragma unroll
        for (int j = 0; j < 8; ++j)
          Vt[(d0 + j) * 35 + sp] = (unsigned int)va[j] | ((unsigned int)vb[j] << 16);
      }
      __syncthreads();

      f32x4 ST[4];
#pragma unroll
      for (int i = 0; i < 4; ++i) {
        bf16x8 ak0 = *(const bf16x8*)&Ks[(i * 16 + l16) * 72 + quad * 8];
        bf16x8 ak1 = *(const bf16x8*)&Ks[(i * 16 + l16) * 72 + 32 + quad * 8];
        f32x4 z = {};
        z = __builtin_amdgcn_mfma_f32_16x16x32_bf16(ak0, bq0, z, 0, 0, 0);
        ST[i] = __builtin_amdgcn_mfma_f32_16x16x32_bf16(ak1, bq1, z, 0, 0, 0);
      }

      bool dm = (kt == qt);
      float p[4][4];
      float mx = NEG_BIG;
#pragma unroll
      for (int i = 0; i < 4; ++i)
#pragma unroll
        for (int r = 0; r < 4; ++r) {
          float v = ST[i][r] * EXP2SC;
          int srel = i * 16 + quad * 4 + r;
          if (dm && srel > qrel) v = NEG_BIG;
          p[i][r] = v;
          mx = fmaxf(mx, v);
        }
      mx = fmaxf(mx, __shfl_xor(mx, 16));
      mx = fmaxf(mx, __shfl_xor(mx, 32));
      float mn = fmaxf(m_i, mx);
      float alpha = exp2f(m_i - mn);
      m_i = mn;
      float sum = 0.f;
#pragma unroll
      for (int i = 0; i < 4; ++i)
#pragma unroll
        for (int r = 0; r < 4; ++r) {
          float e = exp2f(p[i][r] - mn);
          p[i][r] = e;
          sum += e;
        }
      sum += __shfl_xor(sum, 16);
      sum += __shfl_xor(sum, 32);
      l_i = alpha * l_i + sum;

#pragma unroll
      for (int i = 0; i < 4; ++i) {
        uint2 pr;
        pr.x = (unsigned int)f2b(p[i][0]) | ((unsigned int)f2b(p[i][1]) << 16);
        pr.y = (unsigned int)f2b(p[i][2]) | ((unsigned int)f2b(p[i][3]) << 16);
        *(uint2*)(Pw + l16 * 72 + i * 16 + quad * 4) = pr;
      }

      float ar[4];
#pragma unroll
      for (int r = 0; r < 4; ++r)
        ar[r] = __shfl(alpha, (lane & 48) | (quad * 4 + r));
#pragma unroll
      for (int jd = 0; jd < 4; ++jd)
#pragma unroll
        for (int r = 0; r < 4; ++r) O[jd][r] *= ar[r];

#pragma unroll
      for (int ks = 0; ks < 2; ++ks) {
        bf16x8 ap = *(const bf16x8*)(Pw + l16 * 72 + ks * 32 + quad * 8);
#pragma unroll
        for (int jd = 0; jd < 4; ++jd) {
          union { unsigned int u[4]; bf16x8 v; } bv;
          int vbase = (jd * 16 + l16) * 35 + ks * 16 + quad * 4;
#pragma unroll
          for (int cc = 0; cc < 4; ++cc) bv.u[cc] = Vt[vbase + cc];
          O[jd] = __builtin_amdgcn_mfma_f32_16x16x32_bf16(ap, bv.v, O[jd], 0, 0, 0);
        }
      }
      __syncthreads();
    }

    float li[4];
#pragma unroll
    for (int r = 0; r < 4; ++r)
      li[r] = 1.f / __shfl(l_i, (lane & 48) | (quad * 4 + r));
#pragma unroll
    for (int jd = 0; jd < 4; ++jd)
#pragma unroll
      for (int r = 0; r < 4; ++r) {
        size_t row = (size_t)b * 2048 + q0 + w * 16 + quad * 4 + r;
        out[row * 1024 + h * 64 + jd * 16 + l16] = f2b(O[jd][r] * li[r]);
      }
  }
}

// ---------------------------------------------------------------------------
extern "C" void kernel_launch(void* const* d_in, const int* in_sizes, int n_in,
                              void* d_out, int out_size, void* d_ws, size_t ws_size,
                              hipStream_t stream) {
  (void)in_sizes; (void)n_in; (void)out_size;
  const void* x     = d_in[0];
  const void* ln1s  = d_in[2];
  const void* ln1b  = d_in[3];
  const void* ln2s  = d_in[4];
  const void* ln2b  = d_in[5];
  const void* w_qkv = d_in[6];
  const void* b_qkv = d_in[7];
  const void* w_ap  = d_in[8];
  const void* b_ap  = d_in[9];
  const void* w_fc  = d_in[10];
  const void* b_fc  = d_in[11];
  const void* w_mp  = d_in[12];
  const void* b_mp  = d_in[13];
  char* ws = (char*)d_ws;

  const int M = 4096, D = 1024, DFF = 4096, QKV3 = 3072;
  size_t off = 0;
  auto alloc = [&](size_t n) { char* p = ws + off; off += n; return p; };
  int* flag            = (int*)alloc(256);
  unsigned short* wT   = (unsigned short*)alloc((size_t)DFF * D * 2);   // 8 MiB
  unsigned short* hbuf = (unsigned short*)alloc((size_t)M * D * 2);     // 8 MiB (LN out / attn out)
  unsigned short* x1   = (unsigned short*)alloc((size_t)M * D * 2);     // 8 MiB
  char* region = alloc((size_t)M * DFF * 2);                            // 32 MiB
  unsigned short* qkvb = (unsigned short*)region;                       // [4096][3072] 24 MiB
  float* P0a = (float*)region;                                          // 16 MiB (after qkvb dead)
  float* P1a = (float*)(region + (size_t)M * D * 4);                    // 16 MiB
  unsigned short* fcb  = (unsigned short*)region;                       // [4096][4096] 32 MiB
  // mlp-proj split-K partials live past the 56 MiB mark if ws allows
  bool mlpSplit = ws_size >= off + (size_t)M * D * 8 + 1024;
  float* P0m = (float*)(ws + off);
  float* P1m = P0m + (size_t)M * D;

  dim3 blk(256);
  detect_k<<<dim3(1), dim3(64), 0, stream>>>((const unsigned short*)x, flag);
  // --- attention branch ---
  transpose_k<<<dim3(QKV3 / 64, D / 64), blk, 0, stream>>>(w_qkv, wT, D, QKV3, flag);
  ln_k<<<dim3(M), blk, 0, stream>>>(x, ln1s, ln1b, hbuf, flag, 1);
  gemm_bt<0><<<dim3(QKV3 / 128, M / 128), blk, 0, stream>>>(hbuf, wT, b_qkv, nullptr, qkvb, M, QKV3, D, flag, 0, 0);
  attn_k<<<dim3(16, 32), blk, 0, stream>>>(qkvb, hbuf);
  transpose_k<<<dim3(D / 64, D / 64), blk, 0, stream>>>(w_ap, wT, D, D, flag);
  gemm_pk<<<dim3(D / 128, M / 128, 2), blk, 0, stream>>>(hbuf, wT, P0a, M, D, D / 2, D);
  reduce2_k<<<dim3(M * D / 1024), blk, 0, stream>>>(P0a, P1a, b_ap, x, x1, D, flag, 1, 0);
  // --- MLP branch ---
  transpose_k<<<dim3(DFF / 64, D / 64), blk, 0, stream>>>(w_fc, wT, D, DFF, flag);
  ln_k<<<dim3(M), blk, 0, stream>>>(x1, ln2s, ln2b, hbuf, flag, 0);
  gemm_bt<1><<<dim3(DFF / 128, M / 128), blk, 0, stream>>>(hbuf, wT, b_fc, nullptr, fcb, M, DFF, D, flag, 0, 0);
  transpose_k<<<dim3(D / 64, DFF / 64), blk, 0, stream>>>(w_mp, wT, DFF, D, flag);
  if (mlpSplit) {
    gemm_pk<<<dim3(D / 128, M / 128, 2), blk, 0, stream>>>(fcb, wT, P0m, M, D, DFF / 2, DFF);
    reduce2_k<<<dim3(M * D / 1024), blk, 0, stream>>>(P0m, P1m, b_mp, x1, d_out, D, flag, 0, 1);
  } else {
    gemm_bt<2><<<dim3(D / 128, M / 128), blk, 0, stream>>>(fcb, wT, b_mp, x1, d_out, M, D, DFF, flag, 0, 1);
  }
}